// Round 6
// baseline (3486.238 us; speedup 1.0000x reference)
//
#include <hip/hip_runtime.h>
#include <math.h>

// dims
#define BATCH 4
#define SEQ 512
#define DM 1024
#define NH 16
#define DH 64
#define DFF 4096
#define MROWS (BATCH * SEQ)   // 2048

__global__ __launch_bounds__(256) void fill0_kernel(float* __restrict__ out) {
    out[blockIdx.x * 256 + threadIdx.x] = 0.0f;  // ws-too-small sentinel
}

// ---------------- 1) sinusoidal emb + silu ----------------
__global__ void semb_kernel(const int* __restrict__ ts, float* __restrict__ semb) {
    int b = blockIdx.x;
    float x = (float)ts[b] * 40.0f;  // t/100*4000
    for (int j = threadIdx.x; j < 1024; j += 256) {
        int idx = (j < 512) ? j : (j - 512);
        float fr = expf(-9.210340371976184f * (float)idx / 511.0f);
        float e = x * fr;
        float v = (j < 512) ? sinf(e) : cosf(e);
        float sv = v / (1.0f + expf(-v));  // silu
        semb[b * 1024 + j] = sv;
    }
}

// ---------------- 2) ada matvec: ss[b][n] = silu_emb[b] . W_ada[:,n] + b_ada[n] --------
__global__ __launch_bounds__(256) void ada_kernel(const float* __restrict__ semb,
                                                  const float* __restrict__ W,
                                                  const float* __restrict__ bias,
                                                  float* __restrict__ ss) {
    int b = blockIdx.y;
    int n = blockIdx.x * 256 + threadIdx.x;  // 0..2047
    __shared__ float e[1024];
    for (int j = threadIdx.x; j < 1024; j += 256) e[j] = semb[b * 1024 + j];
    __syncthreads();
    float acc = bias[n];
    #pragma unroll 8
    for (int k = 0; k < 1024; ++k) acc += e[k] * W[(size_t)k * 2048 + n];
    ss[b * 2048 + n] = acc;
}

// ---------------- 3) AdaLN: x = LN(src)*(1+scale)+shift  (f32 in/out) --------
__global__ __launch_bounds__(256) void adaln_kernel(const float* __restrict__ src,
                                                    const float* __restrict__ ss,
                                                    float* __restrict__ xb) {
    int r = blockIdx.x;
    int b = r >> 9;
    int t = threadIdx.x;
    float4 v4 = *reinterpret_cast<const float4*>(&src[(size_t)r * DM + t * 4]);
    float v[4] = {v4.x, v4.y, v4.z, v4.w};
    float s = v[0] + v[1] + v[2] + v[3];
    float q = v[0] * v[0] + v[1] * v[1] + v[2] * v[2] + v[3] * v[3];
    #pragma unroll
    for (int off = 32; off > 0; off >>= 1) { s += __shfl_down(s, off); q += __shfl_down(q, off); }
    __shared__ float red[8];
    if ((t & 63) == 0) { red[t >> 6] = s; red[4 + (t >> 6)] = q; }
    __syncthreads();
    s = red[0] + red[1] + red[2] + red[3];
    q = red[4] + red[5] + red[6] + red[7];
    float mean = s * (1.0f / DM);
    float var = q * (1.0f / DM) - mean * mean;
    float rstd = rsqrtf(var + 1e-5f);
    #pragma unroll
    for (int j = 0; j < 4; ++j) {
        int c = t * 4 + j;
        float y = (v[j] - mean) * rstd * (1.0f + ss[b * 2048 + c]) + ss[b * 2048 + 1024 + c];
        xb[(size_t)r * DM + c] = y;
    }
}

// ---------------- LN2: h = LN(x2)*g2+beta2  (f32 in/out) ----------------
__global__ __launch_bounds__(256) void ln2_kernel(const float* __restrict__ x,
                                                  const float* __restrict__ g2,
                                                  const float* __restrict__ beta2,
                                                  float* __restrict__ hout) {
    int r = blockIdx.x;
    int t = threadIdx.x;
    float4 v4 = *reinterpret_cast<const float4*>(&x[(size_t)r * DM + t * 4]);
    float v[4] = {v4.x, v4.y, v4.z, v4.w};
    float s = v[0] + v[1] + v[2] + v[3];
    float q = v[0] * v[0] + v[1] * v[1] + v[2] * v[2] + v[3] * v[3];
    #pragma unroll
    for (int off = 32; off > 0; off >>= 1) { s += __shfl_down(s, off); q += __shfl_down(q, off); }
    __shared__ float red[8];
    if ((t & 63) == 0) { red[t >> 6] = s; red[4 + (t >> 6)] = q; }
    __syncthreads();
    s = red[0] + red[1] + red[2] + red[3];
    q = red[4] + red[5] + red[6] + red[7];
    float mean = s * (1.0f / DM);
    float var = q * (1.0f / DM) - mean * mean;
    float rstd = rsqrtf(var + 1e-5f);
    #pragma unroll
    for (int j = 0; j < 4; ++j) {
        int c = t * 4 + j;
        hout[(size_t)r * DM + c] = (v[j] - mean) * rstd * g2[c] + beta2[c];
    }
}

// ---------------- tiled GEMM: A[M,K] f32 x W[K,N] f32 + bias; act 0/1; resid f32 --------
// In-place allowed when resid == outF (element read once then written by same thread).
#define BM 64
#define BN 64
#define BK 16
__global__ __launch_bounds__(256) void gemm_kernel(const float* __restrict__ A,
                                                   const float* __restrict__ W,
                                                   const float* __restrict__ bias,
                                                   const float* __restrict__ resid,
                                                   float* __restrict__ outF,
                                                   int M, int N, int K, int act) {
    __shared__ float As[BK][BM];
    __shared__ float Bs[BK][BN];
    int t = threadIdx.x;
    int tx = t & 15, ty = t >> 4;
    int m0 = blockIdx.y * BM, n0 = blockIdx.x * BN;
    float acc[4][4] = {};
    for (int k0 = 0; k0 < K; k0 += BK) {
        {
            int r = t >> 2, cb = (t & 3) << 2;
            float4 a4 = *reinterpret_cast<const float4*>(&A[(size_t)(m0 + r) * K + k0 + cb]);
            As[cb + 0][r] = a4.x; As[cb + 1][r] = a4.y;
            As[cb + 2][r] = a4.z; As[cb + 3][r] = a4.w;
            int kr = t >> 4, nb = (t & 15) << 2;
            float4 b4 = *reinterpret_cast<const float4*>(&W[(size_t)(k0 + kr) * N + n0 + nb]);
            Bs[kr][nb + 0] = b4.x; Bs[kr][nb + 1] = b4.y;
            Bs[kr][nb + 2] = b4.z; Bs[kr][nb + 3] = b4.w;
        }
        __syncthreads();
        #pragma unroll
        for (int kk = 0; kk < BK; ++kk) {
            float a[4], bb[4];
            #pragma unroll
            for (int i = 0; i < 4; ++i) a[i] = As[kk][ty * 4 + i];
            #pragma unroll
            for (int j = 0; j < 4; ++j) bb[j] = Bs[kk][tx * 4 + j];
            #pragma unroll
            for (int i = 0; i < 4; ++i)
                #pragma unroll
                for (int j = 0; j < 4; ++j)
                    acc[i][j] = fmaf(a[i], bb[j], acc[i][j]);
        }
        __syncthreads();
    }
    #pragma unroll
    for (int i = 0; i < 4; ++i) {
        int row = m0 + ty * 4 + i;
        #pragma unroll
        for (int j = 0; j < 4; ++j) {
            int col = n0 + tx * 4 + j;
            float v = acc[i][j] + bias[col];
            if (act == 1) v = v / (1.0f + expf(-1.702f * v));
            if (resid) v += resid[(size_t)row * N + col];
            outF[(size_t)row * N + col] = v;
        }
    }
}

// ---------------- attention (one batch b; q/k/v are [SEQ][DM] f32) ----------------
// mask is int32 (numpy bool -> harness integer convention): nonzero => -inf
#define QB 8
__global__ __launch_bounds__(256) void attn_kernel(const float* __restrict__ qbuf,
                                                   const float* __restrict__ kbuf,
                                                   const float* __restrict__ vbuf,
                                                   const float* __restrict__ attb,
                                                   const int* __restrict__ mask,
                                                   float* __restrict__ ctx,
                                                   int b) {
    int q0 = blockIdx.x * QB;
    int h = blockIdx.y;
    int t = threadIdx.x;
    __shared__ float Qs[QB][DH];
    __shared__ float Ks[64][DH + 1];
    __shared__ float Sc[QB][SEQ];
    __shared__ float rowsum[QB];

    for (int e = t; e < QB * DH; e += 256) {
        int qi = e >> 6, d = e & 63;
        Qs[qi][d] = qbuf[(size_t)(q0 + qi) * DM + h * DH + d] * 0.125f;
    }

    for (int kt = 0; kt < 8; ++kt) {
        __syncthreads();
        #pragma unroll
        for (int p = 0; p < 4; ++p) {
            int e = (p * 256 + t) * 4;
            int i = e >> 6, c = e & 63;
            float4 u = *reinterpret_cast<const float4*>(
                &kbuf[(size_t)(kt * 64 + i) * DM + h * DH + c]);
            Ks[i][c + 0] = u.x; Ks[i][c + 1] = u.y; Ks[i][c + 2] = u.z; Ks[i][c + 3] = u.w;
        }
        __syncthreads();
        int ki = t & 63;
        int qi0 = t >> 6;
        #pragma unroll
        for (int half = 0; half < 2; ++half) {
            int qi = qi0 + half * 4;
            float dot = 0.0f;
            #pragma unroll 16
            for (int j = 0; j < DH; ++j) dot += Qs[qi][j] * Ks[ki][j];
            int kg = kt * 64 + ki;
            float sc = dot + attb[(((size_t)(b * NH + h)) * SEQ + (q0 + qi)) * SEQ + kg];
            if (mask[((size_t)b * SEQ + (q0 + qi)) * SEQ + kg]) sc = -INFINITY;
            Sc[qi][kg] = sc;
        }
    }
    __syncthreads();

    {
        int qi = t >> 5;
        int g = t & 31;
        float mx = -INFINITY;
        for (int k = g; k < SEQ; k += 32) mx = fmaxf(mx, Sc[qi][k]);
        #pragma unroll
        for (int off = 16; off > 0; off >>= 1) mx = fmaxf(mx, __shfl_xor(mx, off, 32));
        float sum = 0.0f;
        for (int k = g; k < SEQ; k += 32) {
            float p = expf(Sc[qi][k] - mx);
            Sc[qi][k] = p;
            sum += p;
        }
        #pragma unroll
        for (int off = 16; off > 0; off >>= 1) sum += __shfl_xor(sum, off, 32);
        if (g == 0) rowsum[qi] = sum;
    }

    int d = t & 63;
    int qa = t >> 6;
    float acc0 = 0.0f, acc1 = 0.0f;
    for (int kt = 0; kt < 8; ++kt) {
        __syncthreads();
        #pragma unroll
        for (int p = 0; p < 4; ++p) {
            int e = (p * 256 + t) * 4;
            int i = e >> 6, c = e & 63;
            float4 u = *reinterpret_cast<const float4*>(
                &vbuf[(size_t)(kt * 64 + i) * DM + h * DH + c]);
            Ks[i][c + 0] = u.x; Ks[i][c + 1] = u.y; Ks[i][c + 2] = u.z; Ks[i][c + 3] = u.w;
        }
        __syncthreads();
        #pragma unroll 8
        for (int i = 0; i < 64; ++i) {
            float vv = Ks[i][d];
            acc0 = fmaf(Sc[qa][kt * 64 + i], vv, acc0);
            acc1 = fmaf(Sc[qa + 4][kt * 64 + i], vv, acc1);
        }
    }
    float s0 = rowsum[qa], s1 = rowsum[qa + 4];
    ctx[(size_t)(q0 + qa) * DM + h * DH + d] = acc0 / s0;
    ctx[(size_t)(q0 + qa + 4) * DM + h * DH + d] = acc1 / s1;
}

// ---------------- host launch ----------------
extern "C" void kernel_launch(void* const* d_in, const int* in_sizes, int n_in,
                              void* d_out, int out_size, void* d_ws, size_t ws_size,
                              hipStream_t stream) {
    const float* src  = (const float*)d_in[0];
    const int*   mask = (const int*)d_in[1];   // numpy bool -> int32 on device
    const int*   ts   = (const int*)d_in[2];
    const float* attb = (const float*)d_in[3];
    const float* Wada = (const float*)d_in[4];
    const float* bada = (const float*)d_in[5];
    const float* Wq   = (const float*)d_in[6];
    const float* bq   = (const float*)d_in[7];
    const float* Wk   = (const float*)d_in[8];
    const float* bk   = (const float*)d_in[9];
    const float* Wv   = (const float*)d_in[10];
    const float* bv   = (const float*)d_in[11];
    const float* Wo   = (const float*)d_in[12];
    const float* bo   = (const float*)d_in[13];
    const float* W1   = (const float*)d_in[14];
    const float* b1   = (const float*)d_in[15];
    const float* W2   = (const float*)d_in[16];
    const float* b2   = (const float*)d_in[17];
    const float* g2   = (const float*)d_in[18];
    const float* bt2  = (const float*)d_in[19];
    float* out = (float*)d_out;

    const size_t MB = 1024 * 1024;
    const size_t NEED = 65536 + 12 * MB;
    if (ws_size < NEED) {
        fill0_kernel<<<(size_t)MROWS * DM / 256, 256, 0, stream>>>(out);
        return;
    }

    char* ws = (char*)d_ws;
    float* semb = (float*)(ws + 4096);
    float* ss   = (float*)(ws + 24576);
    float* xb   = (float*)(ws + 65536);            // 8MB: xb, becomes x2 in-place
    float* midc = (float*)(ws + 65536 + 8 * MB);   // 4MB: FFN mid chunk (256x4096 f32)
    // d_out scratch: per-batch q/k/v/ctx (2MB each), later h (8MB)
    float* qb  = out;                  // [SEQ][DM]
    float* kb2 = out + 512 * 1024;     // elems
    float* vb2 = out + 2 * 512 * 1024;
    float* ctx = out + 3 * 512 * 1024;
    float* hb  = out;                  // [MROWS][DM] after attention
    float* x2  = xb;                   // in-place rename

    semb_kernel<<<4, 256, 0, stream>>>(ts, semb);
    ada_kernel<<<dim3(8, 4), 256, 0, stream>>>(semb, Wada, bada, ss);
    adaln_kernel<<<MROWS, 256, 0, stream>>>(src, ss, xb);

    for (int b = 0; b < BATCH; ++b) {
        float* xrows = xb + (size_t)b * SEQ * DM;
        gemm_kernel<<<dim3(DM / BN, SEQ / BM), 256, 0, stream>>>(xrows, Wq, bq, nullptr, qb,
                                                                 SEQ, DM, DM, 0);
        gemm_kernel<<<dim3(DM / BN, SEQ / BM), 256, 0, stream>>>(xrows, Wk, bk, nullptr, kb2,
                                                                 SEQ, DM, DM, 0);
        gemm_kernel<<<dim3(DM / BN, SEQ / BM), 256, 0, stream>>>(xrows, Wv, bv, nullptr, vb2,
                                                                 SEQ, DM, DM, 0);
        attn_kernel<<<dim3(SEQ / QB, NH), 256, 0, stream>>>(qb, kb2, vb2, attb, mask, ctx, b);
        // x2_b = xb_b + ctx_b@Wo + bo   (in-place over xb_b)
        gemm_kernel<<<dim3(DM / BN, SEQ / BM), 256, 0, stream>>>(ctx, Wo, bo, xrows, xrows,
                                                                 SEQ, DM, DM, 0);
    }
    // h = LN2(x2) -> d_out (q/k/v/ctx dead)
    ln2_kernel<<<MROWS, 256, 0, stream>>>(x2, g2, bt2, hb);
    // FFN in 8 row-chunks; W2-gemm overwrites d_out rows already consumed by W1-gemm
    for (int rc = 0; rc < 8; ++rc) {
        const float* hrows = hb + (size_t)rc * 256 * DM;
        const float* xrows = x2 + (size_t)rc * 256 * DM;
        float* orows = out + (size_t)rc * 256 * DM;
        gemm_kernel<<<dim3(DFF / BN, 256 / BM), 256, 0, stream>>>(hrows, W1, b1, nullptr, midc,
                                                                  256, DFF, DM, 1);
        gemm_kernel<<<dim3(DM / BN, 256 / BM), 256, 0, stream>>>(midc, W2, b2, xrows, orows,
                                                                 256, DM, DFF, 0);
    }
}

// Round 7
// 544.157 us; speedup vs baseline: 6.4067x; 6.4067x over previous
//
#include <hip/hip_runtime.h>
#include <math.h>

typedef __bf16 bf16x8 __attribute__((ext_vector_type(8)));
typedef float  f32x4  __attribute__((ext_vector_type(4)));
typedef unsigned short u16x8 __attribute__((ext_vector_type(8)));

__device__ __forceinline__ float bf2f(unsigned short u) {
    return __uint_as_float(((unsigned int)u) << 16);
}
__device__ __forceinline__ unsigned short f2bf(float f) {
    unsigned int x = __float_as_uint(f);
    return (unsigned short)((x + 0x7FFFu + ((x >> 16) & 1u)) >> 16);  // RNE
}
__device__ __forceinline__ void unpack8(const uint4 u, float* dst) {
    dst[0] = __uint_as_float(u.x << 16); dst[1] = __uint_as_float(u.x & 0xFFFF0000u);
    dst[2] = __uint_as_float(u.y << 16); dst[3] = __uint_as_float(u.y & 0xFFFF0000u);
    dst[4] = __uint_as_float(u.z << 16); dst[5] = __uint_as_float(u.z & 0xFFFF0000u);
    dst[6] = __uint_as_float(u.w << 16); dst[7] = __uint_as_float(u.w & 0xFFFF0000u);
}

// dims
#define BATCH 4
#define SEQ 512
#define DM 1024
#define NH 16
#define DH 64
#define DFF 4096
#define MROWS (BATCH * SEQ)   // 2048

__global__ __launch_bounds__(256) void fill0_kernel(float* __restrict__ out) {
    out[blockIdx.x * 256 + threadIdx.x] = 0.0f;  // ws-too-small sentinel
}

// ---------------- 1) sinusoidal emb + silu ----------------
__global__ void semb_kernel(const int* __restrict__ ts, float* __restrict__ semb) {
    int b = blockIdx.x;
    float x = (float)ts[b] * 40.0f;
    for (int j = threadIdx.x; j < 1024; j += 256) {
        int idx = (j < 512) ? j : (j - 512);
        float fr = expf(-9.210340371976184f * (float)idx / 511.0f);
        float e = x * fr;
        float v = (j < 512) ? sinf(e) : cosf(e);
        semb[b * 1024 + j] = v / (1.0f + expf(-v));
    }
}

// ---------------- 2) ada matvec ----------------
__global__ __launch_bounds__(256) void ada_kernel(const float* __restrict__ semb,
                                                  const float* __restrict__ W,
                                                  const float* __restrict__ bias,
                                                  float* __restrict__ ss) {
    int b = blockIdx.y;
    int n = blockIdx.x * 256 + threadIdx.x;
    __shared__ float e[1024];
    for (int j = threadIdx.x; j < 1024; j += 256) e[j] = semb[b * 1024 + j];
    __syncthreads();
    float acc = bias[n];
    #pragma unroll 8
    for (int k = 0; k < 1024; ++k) acc += e[k] * W[(size_t)k * 2048 + n];
    ss[b * 2048 + n] = acc;
}

// ---------------- 3) AdaLN: f32 src -> bf16 xb ----------------
__global__ __launch_bounds__(256) void adaln_kernel(const float* __restrict__ src,
                                                    const float* __restrict__ ss,
                                                    unsigned short* __restrict__ xb) {
    int r = blockIdx.x;
    int b = r >> 9;
    int t = threadIdx.x;
    float4 v4 = *reinterpret_cast<const float4*>(&src[(size_t)r * DM + t * 4]);
    float v[4] = {v4.x, v4.y, v4.z, v4.w};
    float s = v[0] + v[1] + v[2] + v[3];
    float q = v[0]*v[0] + v[1]*v[1] + v[2]*v[2] + v[3]*v[3];
    #pragma unroll
    for (int off = 32; off > 0; off >>= 1) { s += __shfl_down(s, off); q += __shfl_down(q, off); }
    __shared__ float red[8];
    if ((t & 63) == 0) { red[t >> 6] = s; red[4 + (t >> 6)] = q; }
    __syncthreads();
    s = red[0] + red[1] + red[2] + red[3];
    q = red[4] + red[5] + red[6] + red[7];
    float mean = s * (1.0f / DM);
    float var = q * (1.0f / DM) - mean * mean;
    float rstd = rsqrtf(var + 1e-5f);
    ushort4 o;
    o.x = f2bf((v[0]-mean)*rstd*(1.0f+ss[b*2048 + t*4+0]) + ss[b*2048+1024 + t*4+0]);
    o.y = f2bf((v[1]-mean)*rstd*(1.0f+ss[b*2048 + t*4+1]) + ss[b*2048+1024 + t*4+1]);
    o.z = f2bf((v[2]-mean)*rstd*(1.0f+ss[b*2048 + t*4+2]) + ss[b*2048+1024 + t*4+2]);
    o.w = f2bf((v[3]-mean)*rstd*(1.0f+ss[b*2048 + t*4+3]) + ss[b*2048+1024 + t*4+3]);
    *reinterpret_cast<ushort4*>(&xb[(size_t)r * DM + t * 4]) = o;
}

// ---------------- LN2: bf16 -> bf16 ----------------
__global__ __launch_bounds__(256) void ln2_kernel(const unsigned short* __restrict__ x,
                                                  const float* __restrict__ g2,
                                                  const float* __restrict__ beta2,
                                                  unsigned short* __restrict__ hout) {
    int r = blockIdx.x;
    int t = threadIdx.x;
    ushort4 s4 = *reinterpret_cast<const ushort4*>(&x[(size_t)r * DM + t * 4]);
    float v[4] = {bf2f(s4.x), bf2f(s4.y), bf2f(s4.z), bf2f(s4.w)};
    float s = v[0] + v[1] + v[2] + v[3];
    float q = v[0]*v[0] + v[1]*v[1] + v[2]*v[2] + v[3]*v[3];
    #pragma unroll
    for (int off = 32; off > 0; off >>= 1) { s += __shfl_down(s, off); q += __shfl_down(q, off); }
    __shared__ float red[8];
    if ((t & 63) == 0) { red[t >> 6] = s; red[4 + (t >> 6)] = q; }
    __syncthreads();
    s = red[0] + red[1] + red[2] + red[3];
    q = red[4] + red[5] + red[6] + red[7];
    float mean = s * (1.0f / DM);
    float var = q * (1.0f / DM) - mean * mean;
    float rstd = rsqrtf(var + 1e-5f);
    ushort4 o;
    o.x = f2bf((v[0]-mean)*rstd*g2[t*4+0] + beta2[t*4+0]);
    o.y = f2bf((v[1]-mean)*rstd*g2[t*4+1] + beta2[t*4+1]);
    o.z = f2bf((v[2]-mean)*rstd*g2[t*4+2] + beta2[t*4+2]);
    o.w = f2bf((v[3]-mean)*rstd*g2[t*4+3] + beta2[t*4+3]);
    *reinterpret_cast<ushort4*>(&hout[(size_t)r * DM + t * 4]) = o;
}

// ---------------- MFMA GEMM: A[M,K] bf16 x W[K,N] f32 (cvt->bf16) ----------------
// tile 64x128x64, 4 waves (2x2), wave tile 32x64 (2x4 of 16x16 mfma)
// MODE: 0 ->bf16; 1 +resid->bf16; 2 gelu2->bf16; 3 +bias+resid->f32; 4 accum->f32 (no bias)
#define TBM 64
#define TBN 128
#define TBK 64
#define ROWA 72   // ushorts per As row (64 + 8 pad), 144 B (16B-aligned)
#define ROWB 72

template<int MODE>
__global__ __launch_bounds__(256) void mfma_gemm(
    const unsigned short* __restrict__ A,
    const float* __restrict__ W,
    const float* __restrict__ bias,
    const unsigned short* __restrict__ resid,
    unsigned short* __restrict__ outB,
    float* __restrict__ outF,
    int M, int N, int K, int ldw)
{
    __shared__ unsigned short As[TBM * ROWA];
    __shared__ unsigned short Bs[TBN * ROWB];
    const int t = threadIdx.x;
    const int lane = t & 63;
    const int w = t >> 6, wm = w >> 1, wn = w & 1;
    const int l15 = lane & 15, l4 = lane >> 4;
    const int m0 = blockIdx.y * TBM, n0 = blockIdx.x * TBN;

    f32x4 acc[2][4];
    #pragma unroll
    for (int i = 0; i < 2; ++i)
        #pragma unroll
        for (int j = 0; j < 4; ++j)
            #pragma unroll
            for (int r = 0; r < 4; ++r) acc[i][j][r] = 0.0f;

    // staging maps
    const int ar = t >> 2, aseg = t & 3;                 // A: 64 rows x 4 segs of 16 ushorts
    const unsigned short* aG = A + (size_t)(m0 + ar) * K + aseg * 16;
    unsigned short* aL = As + ar * ROWA + aseg * 16;
    const int bn = t & 127, bb0 = t >> 7;                // B: n column, base k-block
    const float* wG = W + (n0 + bn);
    unsigned short* bL = Bs + bn * ROWB;
    const int bswz = bn & 7;

    for (int k0 = 0; k0 < K; k0 += TBK) {
        u16x8 a0 = *(const u16x8*)(aG + k0);
        u16x8 a1 = *(const u16x8*)(aG + k0 + 8);
        float wv[4][8];
        #pragma unroll
        for (int b = 0; b < 4; ++b) {
            const int kb = (bb0 + 2 * b) * 8;
            #pragma unroll
            for (int j = 0; j < 8; ++j)
                wv[b][j] = wG[(size_t)(k0 + kb + j) * ldw];
        }
        __syncthreads();
        *(u16x8*)aL = a0;
        *(u16x8*)(aL + 8) = a1;
        #pragma unroll
        for (int b = 0; b < 4; ++b) {
            const int blk = bb0 + 2 * b;
            u16x8 bv;
            #pragma unroll
            for (int j = 0; j < 8; ++j) bv[j] = f2bf(wv[b][j]);
            *(u16x8*)(bL + ((blk ^ bswz) * 8)) = bv;
        }
        __syncthreads();
        #pragma unroll
        for (int kk = 0; kk < 2; ++kk) {
            bf16x8 af[2], bfr[4];
            #pragma unroll
            for (int mt = 0; mt < 2; ++mt) {
                u16x8 tmp = *(const u16x8*)(As + (wm*32 + mt*16 + l15) * ROWA + kk*32 + l4*8);
                af[mt] = __builtin_bit_cast(bf16x8, tmp);
            }
            #pragma unroll
            for (int nt = 0; nt < 4; ++nt) {
                const int n = wn*64 + nt*16 + l15;
                const int blk = kk*4 + l4;
                u16x8 tmp = *(const u16x8*)(Bs + n * ROWB + ((blk ^ (n & 7)) * 8));
                bfr[nt] = __builtin_bit_cast(bf16x8, tmp);
            }
            #pragma unroll
            for (int mt = 0; mt < 2; ++mt)
                #pragma unroll
                for (int nt = 0; nt < 4; ++nt)
                    acc[mt][nt] = __builtin_amdgcn_mfma_f32_16x16x32_bf16(
                        af[mt], bfr[nt], acc[mt][nt], 0, 0, 0);
        }
    }

    // epilogue: D[row][col] with col=lane&15, row=(lane>>4)*4+reg  [HW-verified]
    #pragma unroll
    for (int mt = 0; mt < 2; ++mt) {
        const int mbase = m0 + wm*32 + mt*16 + l4*4;
        #pragma unroll
        for (int nt = 0; nt < 4; ++nt) {
            const int n = n0 + wn*64 + nt*16 + l15;
            const float bs = (MODE == 4) ? 0.0f : bias[n];
            #pragma unroll
            for (int r = 0; r < 4; ++r) {
                const int m = mbase + r;
                float v = acc[mt][nt][r] + bs;
                if (MODE == 2) v = v / (1.0f + expf(-1.702f * v));
                if (MODE == 1 || MODE == 3) v += bf2f(resid[(size_t)m * N + n]);
                if (MODE == 3)      outF[(size_t)m * N + n] = v;
                else if (MODE == 4) outF[(size_t)m * N + n] += v;
                else                outB[(size_t)m * N + n] = f2bf(v);
            }
        }
    }
}

// ---------------- attention (bf16 q/k/v, f32 softmax) ----------------
#define QB 8
__global__ __launch_bounds__(256) void attn_kernel(const unsigned short* __restrict__ qbuf,
                                                   const unsigned short* __restrict__ kbuf,
                                                   const unsigned short* __restrict__ vbuf,
                                                   const float* __restrict__ attb,
                                                   const int* __restrict__ mask,
                                                   unsigned short* __restrict__ ctx) {
    int q0 = blockIdx.x * QB;
    int h = blockIdx.y;
    int b = blockIdx.z;
    int t = threadIdx.x;
    __shared__ float Qs[QB][DH];
    __shared__ float Ks[64][DH + 1];
    __shared__ float Sc[QB][SEQ];
    __shared__ float rowsum[QB];

    for (int e = t; e < QB * DH; e += 256) {
        int qi = e >> 6, d = e & 63;
        Qs[qi][d] = bf2f(qbuf[((size_t)(b * SEQ + q0 + qi)) * DM + h * DH + d]) * 0.125f;
    }

    for (int kt = 0; kt < 8; ++kt) {
        __syncthreads();
        #pragma unroll
        for (int p = 0; p < 2; ++p) {
            int e = (p * 256 + t) * 8;
            int i = e >> 6, c = e & 63;
            uint4 u = *reinterpret_cast<const uint4*>(
                &kbuf[((size_t)(b * SEQ + kt * 64 + i)) * DM + h * DH + c]);
            unpack8(u, &Ks[i][c]);
        }
        __syncthreads();
        int ki = t & 63;
        int qi0 = t >> 6;
        #pragma unroll
        for (int half = 0; half < 2; ++half) {
            int qi = qi0 + half * 4;
            float dot = 0.0f;
            #pragma unroll 16
            for (int j = 0; j < DH; ++j) dot += Qs[qi][j] * Ks[ki][j];
            int kg = kt * 64 + ki;
            float sc = dot + attb[(((size_t)(b * NH + h)) * SEQ + (q0 + qi)) * SEQ + kg];
            if (mask[((size_t)b * SEQ + (q0 + qi)) * SEQ + kg]) sc = -INFINITY;
            Sc[qi][kg] = sc;
        }
    }
    __syncthreads();

    {
        int qi = t >> 5;
        int g = t & 31;
        float mx = -INFINITY;
        for (int k = g; k < SEQ; k += 32) mx = fmaxf(mx, Sc[qi][k]);
        #pragma unroll
        for (int off = 16; off > 0; off >>= 1) mx = fmaxf(mx, __shfl_xor(mx, off, 32));
        float sum = 0.0f;
        for (int k = g; k < SEQ; k += 32) {
            float p = expf(Sc[qi][k] - mx);
            Sc[qi][k] = p;
            sum += p;
        }
        #pragma unroll
        for (int off = 16; off > 0; off >>= 1) sum += __shfl_xor(sum, off, 32);
        if (g == 0) rowsum[qi] = sum;
    }

    int d = t & 63;
    int qa = t >> 6;
    float acc0 = 0.0f, acc1 = 0.0f;
    for (int kt = 0; kt < 8; ++kt) {
        __syncthreads();
        #pragma unroll
        for (int p = 0; p < 2; ++p) {
            int e = (p * 256 + t) * 8;
            int i = e >> 6, c = e & 63;
            uint4 u = *reinterpret_cast<const uint4*>(
                &vbuf[((size_t)(b * SEQ + kt * 64 + i)) * DM + h * DH + c]);
            unpack8(u, &Ks[i][c]);
        }
        __syncthreads();
        #pragma unroll 8
        for (int i = 0; i < 64; ++i) {
            float vv = Ks[i][d];
            acc0 = fmaf(Sc[qa][kt * 64 + i], vv, acc0);
            acc1 = fmaf(Sc[qa + 4][kt * 64 + i], vv, acc1);
        }
    }
    float s0 = rowsum[qa], s1 = rowsum[qa + 4];
    ctx[((size_t)(b * SEQ + q0 + qa)) * DM + h * DH + d] = f2bf(acc0 / s0);
    ctx[((size_t)(b * SEQ + q0 + qa + 4)) * DM + h * DH + d] = f2bf(acc1 / s1);
}

// ---------------- host launch ----------------
extern "C" void kernel_launch(void* const* d_in, const int* in_sizes, int n_in,
                              void* d_out, int out_size, void* d_ws, size_t ws_size,
                              hipStream_t stream) {
    const float* src  = (const float*)d_in[0];
    const int*   mask = (const int*)d_in[1];
    const int*   ts   = (const int*)d_in[2];
    const float* attb = (const float*)d_in[3];
    const float* Wada = (const float*)d_in[4];
    const float* bada = (const float*)d_in[5];
    const float* Wq   = (const float*)d_in[6];
    const float* bq   = (const float*)d_in[7];
    const float* Wk   = (const float*)d_in[8];
    const float* bk   = (const float*)d_in[9];
    const float* Wv   = (const float*)d_in[10];
    const float* bv   = (const float*)d_in[11];
    const float* Wo   = (const float*)d_in[12];
    const float* bo   = (const float*)d_in[13];
    const float* W1   = (const float*)d_in[14];
    const float* b1   = (const float*)d_in[15];
    const float* W2   = (const float*)d_in[16];
    const float* b2   = (const float*)d_in[17];
    const float* g2   = (const float*)d_in[18];
    const float* bt2  = (const float*)d_in[19];
    float* out = (float*)d_out;

    const size_t MB = 1024 * 1024;
    const size_t NEED = 65536 + 12 * MB;
    if (ws_size < NEED) {
        fill0_kernel<<<(size_t)MROWS * DM / 256, 256, 0, stream>>>(out);
        return;
    }

    char* ws = (char*)d_ws;
    float* semb = (float*)(ws + 4096);
    float* ss   = (float*)(ws + 24576);
    char*  base = ws + 65536;
    unsigned short* slotA = (unsigned short*)(base);            // xb -> mid
    unsigned short* slotB = (unsigned short*)(base + 4 * MB);   // qb -> x2
    unsigned short* slotC = (unsigned short*)(base + 8 * MB);   // kb -> h
    unsigned short* vb   = (unsigned short*)d_out;               // 4 MB
    unsigned short* ctxb = (unsigned short*)((char*)d_out + 4 * MB);
    unsigned short* xb = slotA;
    unsigned short* qb = slotB;
    unsigned short* kb = slotC;
    unsigned short* x2 = slotB;
    unsigned short* hb = slotC;
    unsigned short* mid = slotA;

    semb_kernel<<<4, 256, 0, stream>>>(ts, semb);
    ada_kernel<<<dim3(8, 4), 256, 0, stream>>>(semb, Wada, bada, ss);
    adaln_kernel<<<MROWS, 256, 0, stream>>>(src, ss, xb);

    dim3 g1(DM / TBN, MROWS / TBM);  // (8, 32)
    mfma_gemm<0><<<g1, 256, 0, stream>>>(xb, Wq, bq, nullptr, qb, nullptr,
                                         MROWS, DM, DM, DM);
    mfma_gemm<0><<<g1, 256, 0, stream>>>(xb, Wk, bk, nullptr, kb, nullptr,
                                         MROWS, DM, DM, DM);
    mfma_gemm<0><<<g1, 256, 0, stream>>>(xb, Wv, bv, nullptr, vb, nullptr,
                                         MROWS, DM, DM, DM);
    attn_kernel<<<dim3(SEQ / QB, NH, BATCH), 256, 0, stream>>>(qb, kb, vb, attb, mask, ctxb);
    // x2 = xb + ctx@Wo + bo
    mfma_gemm<1><<<g1, 256, 0, stream>>>(ctxb, Wo, bo, xb, x2, nullptr,
                                         MROWS, DM, DM, DM);
    ln2_kernel<<<MROWS, 256, 0, stream>>>(x2, g2, bt2, hb);
    // FFN: 4 N-chunks of W1 -> mid; W2 row-chunk partials accumulate into f32 out
    for (int nc = 0; nc < 4; ++nc) {
        mfma_gemm<2><<<g1, 256, 0, stream>>>(hb, W1 + nc * 1024, b1 + nc * 1024, nullptr,
                                             mid, nullptr, MROWS, DM, DM, DFF);
        if (nc == 0)
            mfma_gemm<3><<<g1, 256, 0, stream>>>(mid, W2 + (size_t)nc * 1024 * DM, b2, x2,
                                                 nullptr, out, MROWS, DM, DM, DM);
        else
            mfma_gemm<4><<<g1, 256, 0, stream>>>(mid, W2 + (size_t)nc * 1024 * DM, nullptr,
                                                 nullptr, nullptr, out, MROWS, DM, DM, DM);
    }
}

// Round 8
// 375.409 us; speedup vs baseline: 9.2865x; 1.4495x over previous
//
#include <hip/hip_runtime.h>
#include <math.h>

typedef __bf16 bf16x8 __attribute__((ext_vector_type(8)));
typedef float  f32x4  __attribute__((ext_vector_type(4)));
typedef unsigned short u16x8 __attribute__((ext_vector_type(8)));

__device__ __forceinline__ float bf2f(unsigned short u) {
    return __uint_as_float(((unsigned int)u) << 16);
}
__device__ __forceinline__ unsigned short f2bf(float f) {
    unsigned int x = __float_as_uint(f);
    return (unsigned short)((x + 0x7FFFu + ((x >> 16) & 1u)) >> 16);  // RNE
}

// dims
#define BATCH 4
#define SEQ 512
#define DM 1024
#define NH 16
#define DH 64
#define DFF 4096
#define MROWS (BATCH * SEQ)   // 2048

__global__ __launch_bounds__(256) void fill0_kernel(float* __restrict__ out) {
    out[blockIdx.x * 256 + threadIdx.x] = 0.0f;  // ws-too-small sentinel
}

// ---------------- 1) sinusoidal emb + silu ----------------
__global__ void semb_kernel(const int* __restrict__ ts, float* __restrict__ semb) {
    int b = blockIdx.x;
    float x = (float)ts[b] * 40.0f;
    for (int j = threadIdx.x; j < 1024; j += 256) {
        int idx = (j < 512) ? j : (j - 512);
        float fr = expf(-9.210340371976184f * (float)idx / 511.0f);
        float e = x * fr;
        float v = (j < 512) ? sinf(e) : cosf(e);
        semb[b * 1024 + j] = v / (1.0f + expf(-v));
    }
}

// ---------------- 2) ada matvec ----------------
__global__ __launch_bounds__(256) void ada_kernel(const float* __restrict__ semb,
                                                  const float* __restrict__ W,
                                                  const float* __restrict__ bias,
                                                  float* __restrict__ ss) {
    int b = blockIdx.y;
    int n = blockIdx.x * 256 + threadIdx.x;
    __shared__ float e[1024];
    for (int j = threadIdx.x; j < 1024; j += 256) e[j] = semb[b * 1024 + j];
    __syncthreads();
    float acc = bias[n];
    #pragma unroll 8
    for (int k = 0; k < 1024; ++k) acc += e[k] * W[(size_t)k * 2048 + n];
    ss[b * 2048 + n] = acc;
}

// ---------------- 3) AdaLN: f32 src -> bf16 xb ----------------
__global__ __launch_bounds__(256) void adaln_kernel(const float* __restrict__ src,
                                                    const float* __restrict__ ss,
                                                    unsigned short* __restrict__ xb) {
    int r = blockIdx.x;
    int b = r >> 9;
    int t = threadIdx.x;
    float4 v4 = *reinterpret_cast<const float4*>(&src[(size_t)r * DM + t * 4]);
    float v[4] = {v4.x, v4.y, v4.z, v4.w};
    float s = v[0] + v[1] + v[2] + v[3];
    float q = v[0]*v[0] + v[1]*v[1] + v[2]*v[2] + v[3]*v[3];
    #pragma unroll
    for (int off = 32; off > 0; off >>= 1) { s += __shfl_down(s, off); q += __shfl_down(q, off); }
    __shared__ float red[8];
    if ((t & 63) == 0) { red[t >> 6] = s; red[4 + (t >> 6)] = q; }
    __syncthreads();
    s = red[0] + red[1] + red[2] + red[3];
    q = red[4] + red[5] + red[6] + red[7];
    float mean = s * (1.0f / DM);
    float var = q * (1.0f / DM) - mean * mean;
    float rstd = rsqrtf(var + 1e-5f);
    ushort4 o;
    o.x = f2bf((v[0]-mean)*rstd*(1.0f+ss[b*2048 + t*4+0]) + ss[b*2048+1024 + t*4+0]);
    o.y = f2bf((v[1]-mean)*rstd*(1.0f+ss[b*2048 + t*4+1]) + ss[b*2048+1024 + t*4+1]);
    o.z = f2bf((v[2]-mean)*rstd*(1.0f+ss[b*2048 + t*4+2]) + ss[b*2048+1024 + t*4+2]);
    o.w = f2bf((v[3]-mean)*rstd*(1.0f+ss[b*2048 + t*4+3]) + ss[b*2048+1024 + t*4+3]);
    *reinterpret_cast<ushort4*>(&xb[(size_t)r * DM + t * 4]) = o;
}

// ---------------- LN2: bf16 -> bf16 ----------------
__global__ __launch_bounds__(256) void ln2_kernel(const unsigned short* __restrict__ x,
                                                  const float* __restrict__ g2,
                                                  const float* __restrict__ beta2,
                                                  unsigned short* __restrict__ hout) {
    int r = blockIdx.x;
    int t = threadIdx.x;
    ushort4 s4 = *reinterpret_cast<const ushort4*>(&x[(size_t)r * DM + t * 4]);
    float v[4] = {bf2f(s4.x), bf2f(s4.y), bf2f(s4.z), bf2f(s4.w)};
    float s = v[0] + v[1] + v[2] + v[3];
    float q = v[0]*v[0] + v[1]*v[1] + v[2]*v[2] + v[3]*v[3];
    #pragma unroll
    for (int off = 32; off > 0; off >>= 1) { s += __shfl_down(s, off); q += __shfl_down(q, off); }
    __shared__ float red[8];
    if ((t & 63) == 0) { red[t >> 6] = s; red[4 + (t >> 6)] = q; }
    __syncthreads();
    s = red[0] + red[1] + red[2] + red[3];
    q = red[4] + red[5] + red[6] + red[7];
    float mean = s * (1.0f / DM);
    float var = q * (1.0f / DM) - mean * mean;
    float rstd = rsqrtf(var + 1e-5f);
    ushort4 o;
    o.x = f2bf((v[0]-mean)*rstd*g2[t*4+0] + beta2[t*4+0]);
    o.y = f2bf((v[1]-mean)*rstd*g2[t*4+1] + beta2[t*4+1]);
    o.z = f2bf((v[2]-mean)*rstd*g2[t*4+2] + beta2[t*4+2]);
    o.w = f2bf((v[3]-mean)*rstd*g2[t*4+3] + beta2[t*4+3]);
    *reinterpret_cast<ushort4*>(&hout[(size_t)r * DM + t * 4]) = o;
}

// ---------------- MFMA GEMM (unchanged from round 7, verified) ----------------
#define TBM 64
#define TBN 128
#define TBK 64
#define ROWA 72
#define ROWB 72

template<int MODE>
__global__ __launch_bounds__(256) void mfma_gemm(
    const unsigned short* __restrict__ A,
    const float* __restrict__ W,
    const float* __restrict__ bias,
    const unsigned short* __restrict__ resid,
    unsigned short* __restrict__ outB,
    float* __restrict__ outF,
    int M, int N, int K, int ldw)
{
    __shared__ unsigned short As[TBM * ROWA];
    __shared__ unsigned short Bs[TBN * ROWB];
    const int t = threadIdx.x;
    const int lane = t & 63;
    const int w = t >> 6, wm = w >> 1, wn = w & 1;
    const int l15 = lane & 15, l4 = lane >> 4;
    const int m0 = blockIdx.y * TBM, n0 = blockIdx.x * TBN;

    f32x4 acc[2][4];
    #pragma unroll
    for (int i = 0; i < 2; ++i)
        #pragma unroll
        for (int j = 0; j < 4; ++j)
            #pragma unroll
            for (int r = 0; r < 4; ++r) acc[i][j][r] = 0.0f;

    const int ar = t >> 2, aseg = t & 3;
    const unsigned short* aG = A + (size_t)(m0 + ar) * K + aseg * 16;
    unsigned short* aL = As + ar * ROWA + aseg * 16;
    const int bn = t & 127, bb0 = t >> 7;
    const float* wG = W + (n0 + bn);
    unsigned short* bL = Bs + bn * ROWB;
    const int bswz = bn & 7;

    for (int k0 = 0; k0 < K; k0 += TBK) {
        u16x8 a0 = *(const u16x8*)(aG + k0);
        u16x8 a1 = *(const u16x8*)(aG + k0 + 8);
        float wv[4][8];
        #pragma unroll
        for (int b = 0; b < 4; ++b) {
            const int kb = (bb0 + 2 * b) * 8;
            #pragma unroll
            for (int j = 0; j < 8; ++j)
                wv[b][j] = wG[(size_t)(k0 + kb + j) * ldw];
        }
        __syncthreads();
        *(u16x8*)aL = a0;
        *(u16x8*)(aL + 8) = a1;
        #pragma unroll
        for (int b = 0; b < 4; ++b) {
            const int blk = bb0 + 2 * b;
            u16x8 bv;
            #pragma unroll
            for (int j = 0; j < 8; ++j) bv[j] = f2bf(wv[b][j]);
            *(u16x8*)(bL + ((blk ^ bswz) * 8)) = bv;
        }
        __syncthreads();
        #pragma unroll
        for (int kk = 0; kk < 2; ++kk) {
            bf16x8 af[2], bfr[4];
            #pragma unroll
            for (int mt = 0; mt < 2; ++mt) {
                u16x8 tmp = *(const u16x8*)(As + (wm*32 + mt*16 + l15) * ROWA + kk*32 + l4*8);
                af[mt] = __builtin_bit_cast(bf16x8, tmp);
            }
            #pragma unroll
            for (int nt = 0; nt < 4; ++nt) {
                const int n = wn*64 + nt*16 + l15;
                const int blk = kk*4 + l4;
                u16x8 tmp = *(const u16x8*)(Bs + n * ROWB + ((blk ^ (n & 7)) * 8));
                bfr[nt] = __builtin_bit_cast(bf16x8, tmp);
            }
            #pragma unroll
            for (int mt = 0; mt < 2; ++mt)
                #pragma unroll
                for (int nt = 0; nt < 4; ++nt)
                    acc[mt][nt] = __builtin_amdgcn_mfma_f32_16x16x32_bf16(
                        af[mt], bfr[nt], acc[mt][nt], 0, 0, 0);
        }
    }

    #pragma unroll
    for (int mt = 0; mt < 2; ++mt) {
        const int mbase = m0 + wm*32 + mt*16 + l4*4;
        #pragma unroll
        for (int nt = 0; nt < 4; ++nt) {
            const int n = n0 + wn*64 + nt*16 + l15;
            const float bs = (MODE == 4) ? 0.0f : bias[n];
            #pragma unroll
            for (int r = 0; r < 4; ++r) {
                const int m = mbase + r;
                float v = acc[mt][nt][r] + bs;
                if (MODE == 2) v = v / (1.0f + expf(-1.702f * v));
                if (MODE == 1 || MODE == 3) v += bf2f(resid[(size_t)m * N + n]);
                if (MODE == 3)      outF[(size_t)m * N + n] = v;
                else if (MODE == 4) outF[(size_t)m * N + n] += v;
                else                outB[(size_t)m * N + n] = f2bf(v);
            }
        }
    }
}

// ---------------- MFMA flash attention ----------------
// block: 64 q-rows of one (b,h); 4 waves x 16 q-rows; K-tiles of 128
#define AKT 128
#define KROW 72    // Ks row pitch (64 + 8 pad) ushorts
#define VROW 136   // Vt row pitch (128 + 8 pad) ushorts
#define PROW 136

__global__ __launch_bounds__(256) void attn_mfma(const unsigned short* __restrict__ qbuf,
                                                 const unsigned short* __restrict__ kbuf,
                                                 const unsigned short* __restrict__ vbuf,
                                                 const float* __restrict__ attb,
                                                 const int* __restrict__ mask,
                                                 unsigned short* __restrict__ ctx) {
    __shared__ unsigned short Ks[AKT * KROW];       // 18432 B
    __shared__ unsigned short Vt[DH * VROW];        // 17408 B
    __shared__ unsigned short Pb[4 * 16 * PROW];    // 17408 B
    const int t = threadIdx.x;
    const int lane = t & 63;
    const int w = t >> 6;
    const int l15 = lane & 15, l4 = lane >> 4;
    const int q0 = blockIdx.x * 64;
    const int h = blockIdx.y;
    const int b = blockIdx.z;

    // Q fragments in registers (A-operand: row=l15, k=l4*8+j)
    bf16x8 qf[2];
    {
        const unsigned short* qrow = qbuf + ((size_t)(b * SEQ + q0 + w * 16 + l15)) * DM + h * DH;
        u16x8 t0 = *(const u16x8*)(qrow + l4 * 8);
        u16x8 t1 = *(const u16x8*)(qrow + 32 + l4 * 8);
        qf[0] = __builtin_bit_cast(bf16x8, t0);
        qf[1] = __builtin_bit_cast(bf16x8, t1);
    }

    float m[4] = {-1e30f, -1e30f, -1e30f, -1e30f};
    float l[4] = {0.0f, 0.0f, 0.0f, 0.0f};
    f32x4 o[4];
    #pragma unroll
    for (int dt = 0; dt < 4; ++dt)
        #pragma unroll
        for (int r = 0; r < 4; ++r) o[dt][r] = 0.0f;

    unsigned short* Pw = Pb + w * 16 * PROW;

    for (int kt = 0; kt < SEQ / AKT; ++kt) {
        const int kbase = kt * AKT;
        __syncthreads();
        // stage K tile [128][64]
        {
            const int kr = t >> 1, c0 = (t & 1) * 32;
            const unsigned short* g = kbuf + ((size_t)(b * SEQ + kbase + kr)) * DM + h * DH + c0;
            u16x8 v0 = *(const u16x8*)(g);
            u16x8 v1 = *(const u16x8*)(g + 8);
            u16x8 v2 = *(const u16x8*)(g + 16);
            u16x8 v3 = *(const u16x8*)(g + 24);
            unsigned short* s = Ks + kr * KROW + c0;
            *(u16x8*)s = v0; *(u16x8*)(s + 8) = v1;
            *(u16x8*)(s + 16) = v2; *(u16x8*)(s + 24) = v3;
        }
        // stage V transposed: Vt[d][k], packed u32 (k even|odd)
        {
            const int kp = t & 63;
            unsigned int* vt32 = (unsigned int*)Vt;
            #pragma unroll
            for (int g8 = (t >> 6); g8 < 8; g8 += 4) {
                const unsigned short* ga =
                    vbuf + ((size_t)(b * SEQ + kbase + 2 * kp)) * DM + h * DH + g8 * 8;
                u16x8 va = *(const u16x8*)ga;
                u16x8 vb = *(const u16x8*)(ga + DM);
                #pragma unroll
                for (int j = 0; j < 8; ++j) {
                    const int d = g8 * 8 + j;
                    vt32[d * (VROW / 2) + kp] =
                        (unsigned int)va[j] | ((unsigned int)vb[j] << 16);
                }
            }
        }
        __syncthreads();

        // S = Q K^T  (acc[nt][r]: q-row = l4*4+r, key = nt*16+l15)
        f32x4 acc[8];
        #pragma unroll
        for (int nt = 0; nt < 8; ++nt)
            #pragma unroll
            for (int r = 0; r < 4; ++r) acc[nt][r] = 0.0f;
        #pragma unroll
        for (int kk = 0; kk < 2; ++kk) {
            #pragma unroll
            for (int nt = 0; nt < 8; ++nt) {
                u16x8 tmp = *(const u16x8*)(Ks + (nt * 16 + l15) * KROW + kk * 32 + l4 * 8);
                acc[nt] = __builtin_amdgcn_mfma_f32_16x16x32_bf16(
                    qf[kk], __builtin_bit_cast(bf16x8, tmp), acc[nt], 0, 0, 0);
            }
        }

        // bias + mask + online softmax (scores reuse acc)
        const float* bptr = attb + (((size_t)(b * NH + h)) * SEQ + (q0 + w * 16)) * SEQ + kbase;
        const int* mptr = mask + ((size_t)(b * SEQ) + q0 + w * 16) * SEQ + kbase;
        float pm[4] = {-1e30f, -1e30f, -1e30f, -1e30f};
        #pragma unroll
        for (int nt = 0; nt < 8; ++nt) {
            #pragma unroll
            for (int r = 0; r < 4; ++r) {
                const int qr = l4 * 4 + r;
                const int kc = nt * 16 + l15;
                float sv = acc[nt][r] * 0.125f + bptr[(size_t)qr * SEQ + kc];
                if (mptr[(size_t)qr * SEQ + kc]) sv = -1e30f;
                acc[nt][r] = sv;
                pm[r] = fmaxf(pm[r], sv);
            }
        }
        #pragma unroll
        for (int r = 0; r < 4; ++r) {
            #pragma unroll
            for (int off = 1; off < 16; off <<= 1)
                pm[r] = fmaxf(pm[r], __shfl_xor(pm[r], off));
        }
        float al[4], ps[4];
        #pragma unroll
        for (int r = 0; r < 4; ++r) {
            const float mn = fmaxf(m[r], pm[r]);
            al[r] = __expf(m[r] - mn);
            m[r] = mn;
            ps[r] = 0.0f;
        }
        #pragma unroll
        for (int nt = 0; nt < 8; ++nt) {
            #pragma unroll
            for (int r = 0; r < 4; ++r) {
                const float p = __expf(acc[nt][r] - m[r]);
                acc[nt][r] = p;
                ps[r] += p;
            }
        }
        #pragma unroll
        for (int r = 0; r < 4; ++r) {
            #pragma unroll
            for (int off = 1; off < 16; off <<= 1) ps[r] += __shfl_xor(ps[r], off);
            l[r] = l[r] * al[r] + ps[r];
        }
        #pragma unroll
        for (int dt = 0; dt < 4; ++dt)
            #pragma unroll
            for (int r = 0; r < 4; ++r) o[dt][r] *= al[r];

        // P -> LDS (wave-local), then PV
        #pragma unroll
        for (int nt = 0; nt < 8; ++nt)
            #pragma unroll
            for (int r = 0; r < 4; ++r)
                Pw[(l4 * 4 + r) * PROW + nt * 16 + l15] = f2bf(acc[nt][r]);

        #pragma unroll
        for (int ks = 0; ks < 4; ++ks) {
            u16x8 pa = *(const u16x8*)(Pw + l15 * PROW + ks * 32 + l4 * 8);
            #pragma unroll
            for (int dt = 0; dt < 4; ++dt) {
                u16x8 vv = *(const u16x8*)(Vt + (dt * 16 + l15) * VROW + ks * 32 + l4 * 8);
                o[dt] = __builtin_amdgcn_mfma_f32_16x16x32_bf16(
                    __builtin_bit_cast(bf16x8, pa), __builtin_bit_cast(bf16x8, vv),
                    o[dt], 0, 0, 0);
            }
        }
    }

    // epilogue: ctx[q][h*64+d] = o / l
    #pragma unroll
    for (int r = 0; r < 4; ++r) {
        const float inv = 1.0f / l[r];
        const size_t row = (size_t)(b * SEQ + q0 + w * 16 + l4 * 4 + r) * DM + h * DH;
        #pragma unroll
        for (int dt = 0; dt < 4; ++dt)
            ctx[row + dt * 16 + l15] = f2bf(o[dt][r] * inv);
    }
}

// ---------------- host launch ----------------
extern "C" void kernel_launch(void* const* d_in, const int* in_sizes, int n_in,
                              void* d_out, int out_size, void* d_ws, size_t ws_size,
                              hipStream_t stream) {
    const float* src  = (const float*)d_in[0];
    const int*   mask = (const int*)d_in[1];
    const int*   ts   = (const int*)d_in[2];
    const float* attb = (const float*)d_in[3];
    const float* Wada = (const float*)d_in[4];
    const float* bada = (const float*)d_in[5];
    const float* Wq   = (const float*)d_in[6];
    const float* bq   = (const float*)d_in[7];
    const float* Wk   = (const float*)d_in[8];
    const float* bk   = (const float*)d_in[9];
    const float* Wv   = (const float*)d_in[10];
    const float* bv   = (const float*)d_in[11];
    const float* Wo   = (const float*)d_in[12];
    const float* bo   = (const float*)d_in[13];
    const float* W1   = (const float*)d_in[14];
    const float* b1   = (const float*)d_in[15];
    const float* W2   = (const float*)d_in[16];
    const float* b2   = (const float*)d_in[17];
    const float* g2   = (const float*)d_in[18];
    const float* bt2  = (const float*)d_in[19];
    float* out = (float*)d_out;

    const size_t MB = 1024 * 1024;
    const size_t NEED = 65536 + 12 * MB;
    if (ws_size < NEED) {
        fill0_kernel<<<(size_t)MROWS * DM / 256, 256, 0, stream>>>(out);
        return;
    }

    char* ws = (char*)d_ws;
    float* semb = (float*)(ws + 4096);
    float* ss   = (float*)(ws + 24576);
    char*  base = ws + 65536;
    unsigned short* slotA = (unsigned short*)(base);            // xb -> mid
    unsigned short* slotB = (unsigned short*)(base + 4 * MB);   // qb -> x2
    unsigned short* slotC = (unsigned short*)(base + 8 * MB);   // kb -> h
    unsigned short* vb   = (unsigned short*)d_out;               // 4 MB
    unsigned short* ctxb = (unsigned short*)((char*)d_out + 4 * MB);
    unsigned short* xb = slotA;
    unsigned short* qb = slotB;
    unsigned short* kb = slotC;
    unsigned short* x2 = slotB;
    unsigned short* hb = slotC;
    unsigned short* mid = slotA;

    semb_kernel<<<4, 256, 0, stream>>>(ts, semb);
    ada_kernel<<<dim3(8, 4), 256, 0, stream>>>(semb, Wada, bada, ss);
    adaln_kernel<<<MROWS, 256, 0, stream>>>(src, ss, xb);

    dim3 g1(DM / TBN, MROWS / TBM);  // (8, 32)
    mfma_gemm<0><<<g1, 256, 0, stream>>>(xb, Wq, bq, nullptr, qb, nullptr,
                                         MROWS, DM, DM, DM);
    mfma_gemm<0><<<g1, 256, 0, stream>>>(xb, Wk, bk, nullptr, kb, nullptr,
                                         MROWS, DM, DM, DM);
    mfma_gemm<0><<<g1, 256, 0, stream>>>(xb, Wv, bv, nullptr, vb, nullptr,
                                         MROWS, DM, DM, DM);
    attn_mfma<<<dim3(SEQ / 64, NH, BATCH), 256, 0, stream>>>(qb, kb, vb, attb, mask, ctxb);
    // x2 = xb + ctx@Wo + bo
    mfma_gemm<1><<<g1, 256, 0, stream>>>(ctxb, Wo, bo, xb, x2, nullptr,
                                         MROWS, DM, DM, DM);
    ln2_kernel<<<MROWS, 256, 0, stream>>>(x2, g2, bt2, hb);
    // FFN: 4 N-chunks of W1 -> mid; W2 K-chunk partials accumulate into f32 out
    for (int nc = 0; nc < 4; ++nc) {
        mfma_gemm<2><<<g1, 256, 0, stream>>>(hb, W1 + nc * 1024, b1 + nc * 1024, nullptr,
                                             mid, nullptr, MROWS, DM, DM, DFF);
        if (nc == 0)
            mfma_gemm<3><<<g1, 256, 0, stream>>>(mid, W2 + (size_t)nc * 1024 * DM, b2, x2,
                                                 nullptr, out, MROWS, DM, DM, DM);
        else
            mfma_gemm<4><<<g1, 256, 0, stream>>>(mid, W2 + (size_t)nc * 1024 * DM, nullptr,
                                                 nullptr, nullptr, out, MROWS, DM, DM, DM);
    }
}

// Round 9
// 331.656 us; speedup vs baseline: 10.5116x; 1.1319x over previous
//
#include <hip/hip_runtime.h>
#include <math.h>

typedef __bf16 bf16x8 __attribute__((ext_vector_type(8)));
typedef float  f32x4  __attribute__((ext_vector_type(4)));
typedef unsigned short u16x8 __attribute__((ext_vector_type(8)));

__device__ __forceinline__ float bf2f(unsigned short u) {
    return __uint_as_float(((unsigned int)u) << 16);
}
__device__ __forceinline__ unsigned short f2bf(float f) {
    unsigned int x = __float_as_uint(f);
    return (unsigned short)((x + 0x7FFFu + ((x >> 16) & 1u)) >> 16);  // RNE
}

// dims
#define BATCH 4
#define SEQ 512
#define DM 1024
#define NH 16
#define DH 64
#define DFF 4096
#define MROWS (BATCH * SEQ)   // 2048

__global__ __launch_bounds__(256) void fill0_kernel(float* __restrict__ out) {
    out[blockIdx.x * 256 + threadIdx.x] = 0.0f;  // ws-too-small sentinel
}

// ---------------- 1) sinusoidal emb + silu ----------------
__global__ void semb_kernel(const int* __restrict__ ts, float* __restrict__ semb) {
    int b = blockIdx.x;
    float x = (float)ts[b] * 40.0f;
    for (int j = threadIdx.x; j < 1024; j += 256) {
        int idx = (j < 512) ? j : (j - 512);
        float fr = expf(-9.210340371976184f * (float)idx / 511.0f);
        float e = x * fr;
        float v = (j < 512) ? sinf(e) : cosf(e);
        semb[b * 1024 + j] = v / (1.0f + expf(-v));
    }
}

// ---------------- 2a) ada partials: part[j][b][n] over k-chunk j ----------------
// grid (16 n-chunks, 16 k-chunks); W panel read coalesced; e slice in LDS
__global__ __launch_bounds__(256) void ada_part_kernel(const float* __restrict__ semb,
                                                       const float* __restrict__ W,
                                                       float* __restrict__ part) {
    const int nb = blockIdx.x, kc = blockIdx.y;
    const int t = threadIdx.x;
    __shared__ float e_s[4][64];
    e_s[t >> 6][t & 63] = semb[(t >> 6) * 1024 + kc * 64 + (t & 63)];
    __syncthreads();
    const int n = nb * 128 + (t & 127);
    const int half = t >> 7;  // 0/1 -> k sub-half of 32
    float a0 = 0.f, a1 = 0.f, a2 = 0.f, a3 = 0.f;
    const int kk0 = half * 32;
    #pragma unroll 8
    for (int kk = kk0; kk < kk0 + 32; ++kk) {
        const float w = W[(size_t)(kc * 64 + kk) * 2048 + n];
        a0 += e_s[0][kk] * w; a1 += e_s[1][kk] * w;
        a2 += e_s[2][kk] * w; a3 += e_s[3][kk] * w;
    }
    const int j = kc * 2 + half;  // 0..31
    float* p = part + (size_t)j * 4 * 2048 + n;
    p[0] = a0; p[2048] = a1; p[2 * 2048] = a2; p[3 * 2048] = a3;
}

// ---------------- 2b) ada reduce: ss[b][n] = bias[n] + sum_j part[j][b][n] --------
__global__ __launch_bounds__(256) void ada_red_kernel(const float* __restrict__ part,
                                                      const float* __restrict__ bias,
                                                      float* __restrict__ ss) {
    const int idx = blockIdx.x * 256 + threadIdx.x;  // 0..8191
    const int b = idx >> 11, n = idx & 2047;
    float acc = bias[n];
    #pragma unroll 8
    for (int j = 0; j < 32; ++j) acc += part[((size_t)j * 4 + b) * 2048 + n];
    ss[b * 2048 + n] = acc;
}

// ---------------- 3) AdaLN: f32 src -> bf16 xb ----------------
__global__ __launch_bounds__(256) void adaln_kernel(const float* __restrict__ src,
                                                    const float* __restrict__ ss,
                                                    unsigned short* __restrict__ xb) {
    int r = blockIdx.x;
    int b = r >> 9;
    int t = threadIdx.x;
    float4 v4 = *reinterpret_cast<const float4*>(&src[(size_t)r * DM + t * 4]);
    float v[4] = {v4.x, v4.y, v4.z, v4.w};
    float s = v[0] + v[1] + v[2] + v[3];
    float q = v[0]*v[0] + v[1]*v[1] + v[2]*v[2] + v[3]*v[3];
    #pragma unroll
    for (int off = 32; off > 0; off >>= 1) { s += __shfl_down(s, off); q += __shfl_down(q, off); }
    __shared__ float red[8];
    if ((t & 63) == 0) { red[t >> 6] = s; red[4 + (t >> 6)] = q; }
    __syncthreads();
    s = red[0] + red[1] + red[2] + red[3];
    q = red[4] + red[5] + red[6] + red[7];
    float mean = s * (1.0f / DM);
    float var = q * (1.0f / DM) - mean * mean;
    float rstd = rsqrtf(var + 1e-5f);
    ushort4 o;
    o.x = f2bf((v[0]-mean)*rstd*(1.0f+ss[b*2048 + t*4+0]) + ss[b*2048+1024 + t*4+0]);
    o.y = f2bf((v[1]-mean)*rstd*(1.0f+ss[b*2048 + t*4+1]) + ss[b*2048+1024 + t*4+1]);
    o.z = f2bf((v[2]-mean)*rstd*(1.0f+ss[b*2048 + t*4+2]) + ss[b*2048+1024 + t*4+2]);
    o.w = f2bf((v[3]-mean)*rstd*(1.0f+ss[b*2048 + t*4+3]) + ss[b*2048+1024 + t*4+3]);
    *reinterpret_cast<ushort4*>(&xb[(size_t)r * DM + t * 4]) = o;
}

// ---------------- LN2: bf16 -> bf16 ----------------
__global__ __launch_bounds__(256) void ln2_kernel(const unsigned short* __restrict__ x,
                                                  const float* __restrict__ g2,
                                                  const float* __restrict__ beta2,
                                                  unsigned short* __restrict__ hout) {
    int r = blockIdx.x;
    int t = threadIdx.x;
    ushort4 s4 = *reinterpret_cast<const ushort4*>(&x[(size_t)r * DM + t * 4]);
    float v[4] = {bf2f(s4.x), bf2f(s4.y), bf2f(s4.z), bf2f(s4.w)};
    float s = v[0] + v[1] + v[2] + v[3];
    float q = v[0]*v[0] + v[1]*v[1] + v[2]*v[2] + v[3]*v[3];
    #pragma unroll
    for (int off = 32; off > 0; off >>= 1) { s += __shfl_down(s, off); q += __shfl_down(q, off); }
    __shared__ float red[8];
    if ((t & 63) == 0) { red[t >> 6] = s; red[4 + (t >> 6)] = q; }
    __syncthreads();
    s = red[0] + red[1] + red[2] + red[3];
    q = red[4] + red[5] + red[6] + red[7];
    float mean = s * (1.0f / DM);
    float var = q * (1.0f / DM) - mean * mean;
    float rstd = rsqrtf(var + 1e-5f);
    ushort4 o;
    o.x = f2bf((v[0]-mean)*rstd*g2[t*4+0] + beta2[t*4+0]);
    o.y = f2bf((v[1]-mean)*rstd*g2[t*4+1] + beta2[t*4+1]);
    o.z = f2bf((v[2]-mean)*rstd*g2[t*4+2] + beta2[t*4+2]);
    o.w = f2bf((v[3]-mean)*rstd*g2[t*4+3] + beta2[t*4+3]);
    *reinterpret_cast<ushort4*>(&hout[(size_t)r * DM + t * 4]) = o;
}

// ---------------- MFMA GEMM (unchanged, verified) ----------------
#define TBM 64
#define TBN 128
#define TBK 64
#define ROWA 72
#define ROWB 72

template<int MODE>
__global__ __launch_bounds__(256) void mfma_gemm(
    const unsigned short* __restrict__ A,
    const float* __restrict__ W,
    const float* __restrict__ bias,
    const unsigned short* __restrict__ resid,
    unsigned short* __restrict__ outB,
    float* __restrict__ outF,
    int M, int N, int K, int ldw)
{
    __shared__ unsigned short As[TBM * ROWA];
    __shared__ unsigned short Bs[TBN * ROWB];
    const int t = threadIdx.x;
    const int lane = t & 63;
    const int w = t >> 6, wm = w >> 1, wn = w & 1;
    const int l15 = lane & 15, l4 = lane >> 4;
    const int m0 = blockIdx.y * TBM, n0 = blockIdx.x * TBN;

    f32x4 acc[2][4];
    #pragma unroll
    for (int i = 0; i < 2; ++i)
        #pragma unroll
        for (int j = 0; j < 4; ++j)
            #pragma unroll
            for (int r = 0; r < 4; ++r) acc[i][j][r] = 0.0f;

    const int ar = t >> 2, aseg = t & 3;
    const unsigned short* aG = A + (size_t)(m0 + ar) * K + aseg * 16;
    unsigned short* aL = As + ar * ROWA + aseg * 16;
    const int bn = t & 127, bb0 = t >> 7;
    const float* wG = W + (n0 + bn);
    unsigned short* bL = Bs + bn * ROWB;
    const int bswz = bn & 7;

    for (int k0 = 0; k0 < K; k0 += TBK) {
        u16x8 a0 = *(const u16x8*)(aG + k0);
        u16x8 a1 = *(const u16x8*)(aG + k0 + 8);
        float wv[4][8];
        #pragma unroll
        for (int b = 0; b < 4; ++b) {
            const int kb = (bb0 + 2 * b) * 8;
            #pragma unroll
            for (int j = 0; j < 8; ++j)
                wv[b][j] = wG[(size_t)(k0 + kb + j) * ldw];
        }
        __syncthreads();
        *(u16x8*)aL = a0;
        *(u16x8*)(aL + 8) = a1;
        #pragma unroll
        for (int b = 0; b < 4; ++b) {
            const int blk = bb0 + 2 * b;
            u16x8 bv;
            #pragma unroll
            for (int j = 0; j < 8; ++j) bv[j] = f2bf(wv[b][j]);
            *(u16x8*)(bL + ((blk ^ bswz) * 8)) = bv;
        }
        __syncthreads();
        #pragma unroll
        for (int kk = 0; kk < 2; ++kk) {
            bf16x8 af[2], bfr[4];
            #pragma unroll
            for (int mt = 0; mt < 2; ++mt) {
                u16x8 tmp = *(const u16x8*)(As + (wm*32 + mt*16 + l15) * ROWA + kk*32 + l4*8);
                af[mt] = __builtin_bit_cast(bf16x8, tmp);
            }
            #pragma unroll
            for (int nt = 0; nt < 4; ++nt) {
                const int n = wn*64 + nt*16 + l15;
                const int blk = kk*4 + l4;
                u16x8 tmp = *(const u16x8*)(Bs + n * ROWB + ((blk ^ (n & 7)) * 8));
                bfr[nt] = __builtin_bit_cast(bf16x8, tmp);
            }
            #pragma unroll
            for (int mt = 0; mt < 2; ++mt)
                #pragma unroll
                for (int nt = 0; nt < 4; ++nt)
                    acc[mt][nt] = __builtin_amdgcn_mfma_f32_16x16x32_bf16(
                        af[mt], bfr[nt], acc[mt][nt], 0, 0, 0);
        }
    }

    #pragma unroll
    for (int mt = 0; mt < 2; ++mt) {
        const int mbase = m0 + wm*32 + mt*16 + l4*4;
        #pragma unroll
        for (int nt = 0; nt < 4; ++nt) {
            const int n = n0 + wn*64 + nt*16 + l15;
            const float bs = (MODE == 4) ? 0.0f : bias[n];
            #pragma unroll
            for (int r = 0; r < 4; ++r) {
                const int m = mbase + r;
                float v = acc[mt][nt][r] + bs;
                if (MODE == 2) v = v / (1.0f + expf(-1.702f * v));
                if (MODE == 1 || MODE == 3) v += bf2f(resid[(size_t)m * N + n]);
                if (MODE == 3)      outF[(size_t)m * N + n] = v;
                else if (MODE == 4) outF[(size_t)m * N + n] += v;
                else                outB[(size_t)m * N + n] = f2bf(v);
            }
        }
    }
}

// ---------------- MFMA flash attention (unchanged, verified) ----------------
#define AKT 128
#define KROW 72
#define VROW 136
#define PROW 136

__global__ __launch_bounds__(256) void attn_mfma(const unsigned short* __restrict__ qbuf,
                                                 const unsigned short* __restrict__ kbuf,
                                                 const unsigned short* __restrict__ vbuf,
                                                 const float* __restrict__ attb,
                                                 const int* __restrict__ mask,
                                                 unsigned short* __restrict__ ctx) {
    __shared__ unsigned short Ks[AKT * KROW];
    __shared__ unsigned short Vt[DH * VROW];
    __shared__ unsigned short Pb[4 * 16 * PROW];
    const int t = threadIdx.x;
    const int lane = t & 63;
    const int w = t >> 6;
    const int l15 = lane & 15, l4 = lane >> 4;
    const int q0 = blockIdx.x * 64;
    const int h = blockIdx.y;
    const int b = blockIdx.z;

    bf16x8 qf[2];
    {
        const unsigned short* qrow = qbuf + ((size_t)(b * SEQ + q0 + w * 16 + l15)) * DM + h * DH;
        u16x8 t0 = *(const u16x8*)(qrow + l4 * 8);
        u16x8 t1 = *(const u16x8*)(qrow + 32 + l4 * 8);
        qf[0] = __builtin_bit_cast(bf16x8, t0);
        qf[1] = __builtin_bit_cast(bf16x8, t1);
    }

    float m[4] = {-1e30f, -1e30f, -1e30f, -1e30f};
    float l[4] = {0.0f, 0.0f, 0.0f, 0.0f};
    f32x4 o[4];
    #pragma unroll
    for (int dt = 0; dt < 4; ++dt)
        #pragma unroll
        for (int r = 0; r < 4; ++r) o[dt][r] = 0.0f;

    unsigned short* Pw = Pb + w * 16 * PROW;

    for (int kt = 0; kt < SEQ / AKT; ++kt) {
        const int kbase = kt * AKT;
        __syncthreads();
        {
            const int kr = t >> 1, c0 = (t & 1) * 32;
            const unsigned short* g = kbuf + ((size_t)(b * SEQ + kbase + kr)) * DM + h * DH + c0;
            u16x8 v0 = *(const u16x8*)(g);
            u16x8 v1 = *(const u16x8*)(g + 8);
            u16x8 v2 = *(const u16x8*)(g + 16);
            u16x8 v3 = *(const u16x8*)(g + 24);
            unsigned short* s = Ks + kr * KROW + c0;
            *(u16x8*)s = v0; *(u16x8*)(s + 8) = v1;
            *(u16x8*)(s + 16) = v2; *(u16x8*)(s + 24) = v3;
        }
        {
            const int kp = t & 63;
            unsigned int* vt32 = (unsigned int*)Vt;
            #pragma unroll
            for (int g8 = (t >> 6); g8 < 8; g8 += 4) {
                const unsigned short* ga =
                    vbuf + ((size_t)(b * SEQ + kbase + 2 * kp)) * DM + h * DH + g8 * 8;
                u16x8 va = *(const u16x8*)ga;
                u16x8 vb = *(const u16x8*)(ga + DM);
                #pragma unroll
                for (int j = 0; j < 8; ++j) {
                    const int d = g8 * 8 + j;
                    vt32[d * (VROW / 2) + kp] =
                        (unsigned int)va[j] | ((unsigned int)vb[j] << 16);
                }
            }
        }
        __syncthreads();

        f32x4 acc[8];
        #pragma unroll
        for (int nt = 0; nt < 8; ++nt)
            #pragma unroll
            for (int r = 0; r < 4; ++r) acc[nt][r] = 0.0f;
        #pragma unroll
        for (int kk = 0; kk < 2; ++kk) {
            #pragma unroll
            for (int nt = 0; nt < 8; ++nt) {
                u16x8 tmp = *(const u16x8*)(Ks + (nt * 16 + l15) * KROW + kk * 32 + l4 * 8);
                acc[nt] = __builtin_amdgcn_mfma_f32_16x16x32_bf16(
                    qf[kk], __builtin_bit_cast(bf16x8, tmp), acc[nt], 0, 0, 0);
            }
        }

        const float* bptr = attb + (((size_t)(b * NH + h)) * SEQ + (q0 + w * 16)) * SEQ + kbase;
        const int* mptr = mask + ((size_t)(b * SEQ) + q0 + w * 16) * SEQ + kbase;
        float pm[4] = {-1e30f, -1e30f, -1e30f, -1e30f};
        #pragma unroll
        for (int nt = 0; nt < 8; ++nt) {
            #pragma unroll
            for (int r = 0; r < 4; ++r) {
                const int qr = l4 * 4 + r;
                const int kc = nt * 16 + l15;
                float sv = acc[nt][r] * 0.125f + bptr[(size_t)qr * SEQ + kc];
                if (mptr[(size_t)qr * SEQ + kc]) sv = -1e30f;
                acc[nt][r] = sv;
                pm[r] = fmaxf(pm[r], sv);
            }
        }
        #pragma unroll
        for (int r = 0; r < 4; ++r) {
            #pragma unroll
            for (int off = 1; off < 16; off <<= 1)
                pm[r] = fmaxf(pm[r], __shfl_xor(pm[r], off));
        }
        float al[4], ps[4];
        #pragma unroll
        for (int r = 0; r < 4; ++r) {
            const float mn = fmaxf(m[r], pm[r]);
            al[r] = __expf(m[r] - mn);
            m[r] = mn;
            ps[r] = 0.0f;
        }
        #pragma unroll
        for (int nt = 0; nt < 8; ++nt) {
            #pragma unroll
            for (int r = 0; r < 4; ++r) {
                const float p = __expf(acc[nt][r] - m[r]);
                acc[nt][r] = p;
                ps[r] += p;
            }
        }
        #pragma unroll
        for (int r = 0; r < 4; ++r) {
            #pragma unroll
            for (int off = 1; off < 16; off <<= 1) ps[r] += __shfl_xor(ps[r], off);
            l[r] = l[r] * al[r] + ps[r];
        }
        #pragma unroll
        for (int dt = 0; dt < 4; ++dt)
            #pragma unroll
            for (int r = 0; r < 4; ++r) o[dt][r] *= al[r];

        #pragma unroll
        for (int nt = 0; nt < 8; ++nt)
            #pragma unroll
            for (int r = 0; r < 4; ++r)
                Pw[(l4 * 4 + r) * PROW + nt * 16 + l15] = f2bf(acc[nt][r]);

        #pragma unroll
        for (int ks = 0; ks < 4; ++ks) {
            u16x8 pa = *(const u16x8*)(Pw + l15 * PROW + ks * 32 + l4 * 8);
            #pragma unroll
            for (int dt = 0; dt < 4; ++dt) {
                u16x8 vv = *(const u16x8*)(Vt + (dt * 16 + l15) * VROW + ks * 32 + l4 * 8);
                o[dt] = __builtin_amdgcn_mfma_f32_16x16x32_bf16(
                    __builtin_bit_cast(bf16x8, pa), __builtin_bit_cast(bf16x8, vv),
                    o[dt], 0, 0, 0);
            }
        }
    }

    #pragma unroll
    for (int r = 0; r < 4; ++r) {
        const float inv = 1.0f / l[r];
        const size_t row = (size_t)(b * SEQ + q0 + w * 16 + l4 * 4 + r) * DM + h * DH;
        #pragma unroll
        for (int dt = 0; dt < 4; ++dt)
            ctx[row + dt * 16 + l15] = f2bf(o[dt][r] * inv);
    }
}

// ---------------- host launch ----------------
extern "C" void kernel_launch(void* const* d_in, const int* in_sizes, int n_in,
                              void* d_out, int out_size, void* d_ws, size_t ws_size,
                              hipStream_t stream) {
    const float* src  = (const float*)d_in[0];
    const int*   mask = (const int*)d_in[1];
    const int*   ts   = (const int*)d_in[2];
    const float* attb = (const float*)d_in[3];
    const float* Wada = (const float*)d_in[4];
    const float* bada = (const float*)d_in[5];
    const float* Wq   = (const float*)d_in[6];
    const float* bq   = (const float*)d_in[7];
    const float* Wk   = (const float*)d_in[8];
    const float* bk   = (const float*)d_in[9];
    const float* Wv   = (const float*)d_in[10];
    const float* bv   = (const float*)d_in[11];
    const float* Wo   = (const float*)d_in[12];
    const float* bo   = (const float*)d_in[13];
    const float* W1   = (const float*)d_in[14];
    const float* b1   = (const float*)d_in[15];
    const float* W2   = (const float*)d_in[16];
    const float* b2   = (const float*)d_in[17];
    const float* g2   = (const float*)d_in[18];
    const float* bt2  = (const float*)d_in[19];
    float* out = (float*)d_out;

    const size_t MB = 1024 * 1024;
    const size_t NEED = 65536 + 12 * MB;
    if (ws_size < NEED) {
        fill0_kernel<<<(size_t)MROWS * DM / 256, 256, 0, stream>>>(out);
        return;
    }

    char* ws = (char*)d_ws;
    float* semb = (float*)(ws + 4096);
    float* ss   = (float*)(ws + 24576);
    char*  base = ws + 65536;
    unsigned short* slotA = (unsigned short*)(base);            // xb -> mid
    unsigned short* slotB = (unsigned short*)(base + 4 * MB);   // qb -> x2
    unsigned short* slotC = (unsigned short*)(base + 8 * MB);   // kb -> h
    unsigned short* vb   = (unsigned short*)d_out;               // 4 MB
    unsigned short* ctxb = (unsigned short*)((char*)d_out + 4 * MB);
    unsigned short* xb = slotA;
    unsigned short* qb = slotB;
    unsigned short* kb = slotC;
    unsigned short* x2 = slotB;
    unsigned short* hb = slotC;
    unsigned short* mid = slotA;
    float* adap = (float*)slotC;  // 1 MB ada partials (slotC free pre-adaln)

    semb_kernel<<<4, 256, 0, stream>>>(ts, semb);
    ada_part_kernel<<<dim3(16, 16), 256, 0, stream>>>(semb, Wada, adap);
    ada_red_kernel<<<32, 256, 0, stream>>>(adap, bada, ss);
    adaln_kernel<<<MROWS, 256, 0, stream>>>(src, ss, xb);

    dim3 g1(DM / TBN, MROWS / TBM);  // (8, 32)
    mfma_gemm<0><<<g1, 256, 0, stream>>>(xb, Wq, bq, nullptr, qb, nullptr,
                                         MROWS, DM, DM, DM);
    mfma_gemm<0><<<g1, 256, 0, stream>>>(xb, Wk, bk, nullptr, kb, nullptr,
                                         MROWS, DM, DM, DM);
    mfma_gemm<0><<<g1, 256, 0, stream>>>(xb, Wv, bv, nullptr, vb, nullptr,
                                         MROWS, DM, DM, DM);
    attn_mfma<<<dim3(SEQ / 64, NH, BATCH), 256, 0, stream>>>(qb, kb, vb, attb, mask, ctxb);
    // x2 = xb + ctx@Wo + bo
    mfma_gemm<1><<<g1, 256, 0, stream>>>(ctxb, Wo, bo, xb, x2, nullptr,
                                         MROWS, DM, DM, DM);
    ln2_kernel<<<MROWS, 256, 0, stream>>>(x2, g2, bt2, hb);
    // FFN: 4 N-chunks of W1 -> mid; W2 K-chunk partials accumulate into f32 out
    for (int nc = 0; nc < 4; ++nc) {
        mfma_gemm<2><<<g1, 256, 0, stream>>>(hb, W1 + nc * 1024, b1 + nc * 1024, nullptr,
                                             mid, nullptr, MROWS, DM, DM, DFF);
        if (nc == 0)
            mfma_gemm<3><<<g1, 256, 0, stream>>>(mid, W2 + (size_t)nc * 1024 * DM, b2, x2,
                                                 nullptr, out, MROWS, DM, DM, DM);
        else
            mfma_gemm<4><<<g1, 256, 0, stream>>>(mid, W2 + (size_t)nc * 1024 * DM, nullptr,
                                                 nullptr, nullptr, out, MROWS, DM, DM, DM);
    }
}